// Round 6
// baseline (144.492 us; speedup 1.0000x reference)
//
#include <hip/hip_runtime.h>

typedef __attribute__((ext_vector_type(8))) short short8;
typedef __attribute__((ext_vector_type(4))) float f32x4;

#define CM 256
#define CC 32
#define CZ 128
#define SDIM 128
#define IDIM 256

__device__ __forceinline__ unsigned short f2bf(float f) {
  union { float f; unsigned u; } v; v.f = f;
  unsigned r = v.u + 0x7fffu + ((v.u >> 16) & 1u);
  return (unsigned short)(r >> 16);
}
// pack two f32 -> two bf16 (round-half-up)
__device__ __forceinline__ unsigned pack_bf2(float a, float b) {
  union { float f; unsigned u; } x, y; x.f = a; y.f = b;
  return ((x.u + 0x8000u) >> 16) | ((y.u + 0x8000u) & 0xffff0000u);
}

// ---------------- kernel 0: weight prep ---------------- (unchanged)
__global__ void k_prep(const float* __restrict__ wl, const float* __restrict__ wr,
                       const float* __restrict__ wo,
                       unsigned short* __restrict__ wlrT2, unsigned short* __restrict__ WF) {
  int t = blockIdx.x * 256 + threadIdx.x;
  if (t < 2048) {
    int frag = t >> 6, lane = t & 63;
    int nt = frag >> 3, ks = frag & 7;
    int ln = lane & 15, qd = lane >> 4;
    int c64 = nt * 16 + ln;
#pragma unroll
    for (int e = 0; e < 8; ++e) {
      int cm = ks * 32 + qd * 8 + e;
      float v = (c64 < CC) ? wl[cm * CC + c64] : wr[cm * CC + (c64 - CC)];
      wlrT2[(size_t)t * 8 + e] = f2bf(v);
    }
  } else {
    int t2 = t - 2048;
    if (t2 < 8 * 32 * 64) {
      int zt = t2 >> 11, ks = (t2 >> 6) & 31, lane = t2 & 63;
      int ln = lane & 15, qd = lane >> 4;
      int z = zt * 16 + ln;
#pragma unroll
      for (int e = 0; e < 8; ++e) {
        int c = qd * 8 + e, d = ks;
        WF[(size_t)t2 * 8 + e] = f2bf(wo[(c * 32 + d) * CZ + z] * (1.0f / 128.0f));
      }
    }
  }
}

// ---------------- kernel 1 (v2): LayerNorm + dual projection, 8 waves ----------------
// Same math as v1, remapped: 512 blocks (i, sh) x 512 threads (8 waves).
//   - LN phase: wave ww handles 8 rows (was 16) -> serial latency depth halved;
//     16 waves/CU (was 8) -> 2x TLP. Row loop fully unrolled: 8 independent HBM
//     loads issue together. lnw/lnb hoisted (loop-invariant).
//   - MFMA phase: 8 waves = 4 m-tiles x 2 n-halves (2 n-tiles each, acc[2]).
//   - Stores: waves 0-3 -> A2 fragment slots (rtloc, ksl); waves 4-7 -> Bbuf rows.
__global__ __launch_bounds__(512) void k_lnproj(
    const float* __restrict__ x, const float* __restrict__ lnw, const float* __restrict__ lnb,
    const float* __restrict__ bl, const float* __restrict__ br,
    const unsigned short* __restrict__ wlrT2,
    unsigned short* __restrict__ A2, unsigned short* __restrict__ Bbuf) {
  __shared__ __align__(16) unsigned short xn[64][264];  // 33,792 B
  __shared__ __align__(16) unsigned short sT[64][72];   //  9,216 B
  int tid = threadIdx.x;
  int lane = tid & 63, ww = tid >> 6;      // 8 waves
  int qd = lane >> 4, ln = lane & 15;
  int i = blockIdx.x, sh = blockIdx.y;

  float4 w4 = ((const float4*)lnw)[lane];
  float4 b4 = ((const float4*)lnb)[lane];

  // LN: wave ww handles local rows ww*8 .. +7 (global s = sh*64 + local)
#pragma unroll
  for (int rr = 0; rr < 8; ++rr) {
    int sl = ww * 8 + rr;
    int s = sh * 64 + sl;
    float4 v = ((const float4*)(x + ((size_t)s * IDIM + i) * CM))[lane];
    float s1 = v.x + v.y + v.z + v.w;
    float s2 = v.x * v.x + v.y * v.y + v.z * v.z + v.w * v.w;
#pragma unroll
    for (int off = 32; off; off >>= 1) {
      s1 += __shfl_xor(s1, off);
      s2 += __shfl_xor(s2, off);
    }
    float mu = s1 * (1.0f / 256.0f);
    float var = s2 * (1.0f / 256.0f) - mu * mu;
    float rs = rsqrtf(var + 1e-5f);
    ushort4 h;
    h.x = f2bf((v.x - mu) * rs * w4.x + b4.x);
    h.y = f2bf((v.y - mu) * rs * w4.y + b4.y);
    h.z = f2bf((v.z - mu) * rs * w4.z + b4.z);
    h.w = f2bf((v.w - mu) * rs * w4.w + b4.w);
    *(ushort4*)&xn[sl][lane * 4] = h;
  }
  __syncthreads();

  // project: wave ww = (mt = ww>>1 m-tile, nh = ww&1 n-half), K=256
  int mt = ww >> 1, nh = ww & 1;
  f32x4 acc[2];
#pragma unroll
  for (int t = 0; t < 2; ++t) acc[t] = (f32x4){0.f, 0.f, 0.f, 0.f};
#pragma unroll
  for (int ks = 0; ks < 8; ++ks) {
    short8 af = *(const short8*)&xn[mt * 16 + ln][ks * 32 + qd * 8];
#pragma unroll
    for (int t = 0; t < 2; ++t) {
      int nt = nh * 2 + t;
      short8 bf = *(const short8*)(wlrT2 + ((size_t)((nt * 8 + ks) * 64 + lane)) * 8);
      acc[t] = __builtin_amdgcn_mfma_f32_16x16x32_bf16(af, bf, acc[t], 0, 0, 0);
    }
  }
  // C layout: col(c64)=ln, row(s-local)=qd*4+rg. Bias, transpose via sT[c64][s-local].
#pragma unroll
  for (int t = 0; t < 2; ++t) {
    int nt = nh * 2 + t;
    int c64 = nt * 16 + ln;
    float bias = (c64 < CC) ? bl[c64] : br[c64 - CC];
    ushort4 h;
    h.x = f2bf(acc[t][0] + bias);
    h.y = f2bf(acc[t][1] + bias);
    h.z = f2bf(acc[t][2] + bias);
    h.w = f2bf(acc[t][3] + bias);
    *(ushort4*)&sT[c64][mt * 16 + qd * 4] = h;
  }
  __syncthreads();

  if (ww < 4) {
    // A2 fragment store: wave ww -> (rtloc = ww>>1, ksl = ww&1)
    int rtloc = ww >> 1, ksl = ww & 1;
    short8 v = *(const short8*)&sT[rtloc * 16 + ln][ksl * 32 + qd * 8];
    *(short8*)(A2 + ((size_t)(((2 * i + rtloc) * 4 + (sh * 2 + ksl)) * 64 + lane)) * 8) = v;
  } else {
    // B row-major store: 32 rows x 8 chunks (16B), 256 threads
    int t2 = tid - 256;
    int row = t2 >> 3, ch = t2 & 7;
    short8 v = *(const short8*)&sT[CC + row][ch * 8];
    *(short8*)(Bbuf + ((size_t)(i * CC + row)) * SDIM + sh * 64 + ch * 8) = v;
  }
}

// ---------------- kernel 2 (v6): UNCHANGED from round 5 (A/B isolation) ----------------
__global__ __launch_bounds__(512, 2) void k_main(
    const unsigned short* __restrict__ A2, const unsigned short* __restrict__ Bbuf,
    const unsigned short* __restrict__ WF, const float* __restrict__ bout,
    float* __restrict__ out) {
  extern __shared__ __align__(16) char lds[];
  unsigned short* sPA = (unsigned short*)lds;              // [32][1032]
  unsigned short* sPB = (unsigned short*)(lds + 66048);    // [32][1032]
  unsigned short* sB  = (unsigned short*)(lds + 132096);   // [64][136]
  float* redR = (float*)lds;                               // 32 slots x 1 KB (post-p2)
  int tid = threadIdx.x;
  int lane = tid & 63, ww = tid >> 6;  // 8 waves
  int qd = lane >> 4, ln = lane & 15;
  int bx = blockIdx.x;
  int itile = (bx & 7) * 4 + ((bx >> 3) & 3);  // XCD-affine i-tile (0..31)
  int jg = bx >> 5;                            // j-group (0..31): j = jg*8 .. +7
  int i0 = itile * 8;
  int ztp = ww & 3, kq = ww >> 2;              // p2 wave coords (4 x 2)

  // ---- pinned A-fragments: wave ww owns P-row-tiles rt = i0*2 + ww*2 + ti ----
  short8 afp[2][4];  // [ti][ks] = 8 frags = 32 VGPR
#pragma unroll
  for (int ti = 0; ti < 2; ++ti)
#pragma unroll
    for (int ks = 0; ks < 4; ++ks)
      afp[ti][ks] =
          *(const short8*)(A2 + ((size_t)((i0 * 2 + ww * 2 + ti) * 4 + ks) * 64 + lane) * 8);

  short8 bpre[2];  // B half-tile staging (64 rows x 16 chunks / 512 thr)
#pragma unroll
  for (int tt = 0; tt < 2; ++tt) {
    int idx = tid + tt * 512;
    int r = idx >> 4, ch = idx & 15;
    bpre[tt] = *(const short8*)(Bbuf + ((size_t)(jg * 256 + r)) * SDIM + ch * 8);
  }

#pragma unroll
  for (int q = 0; q < 4; ++q) {
    // ---- stage current B half ----
#pragma unroll
    for (int tt = 0; tt < 2; ++tt) {
      int idx = tid + tt * 512;
      int r = idx >> 4, ch = idx & 15;
      *(short8*)&sB[r * 136 + ch * 8] = bpre[tt];
    }
    __syncthreads();
    // ---- issue next half's loads (hidden under p1) ----
    if (q < 3) {
#pragma unroll
      for (int tt = 0; tt < 2; ++tt) {
        int idx = tid + tt * 512;
        int r = idx >> 4, ch = idx & 15;
        bpre[tt] = *(const short8*)(Bbuf + ((size_t)(jg * 256 + (q + 1) * 64 + r)) * SDIM + ch * 8);
      }
    }
    // ---- p1 pass: P[rows ww*32..+32][64 staged cols] ----
    unsigned short* sP = (q & 2) ? sPB : sPA;
    f32x4 acc1[2][4];
#pragma unroll
    for (int a = 0; a < 2; ++a)
#pragma unroll
      for (int b = 0; b < 4; ++b) acc1[a][b] = (f32x4){0.f, 0.f, 0.f, 0.f};
#pragma unroll
    for (int ks = 0; ks < 4; ++ks)
#pragma unroll
      for (int tjj = 0; tjj < 4; ++tjj) {
        short8 bf = *(const short8*)&sB[(tjj * 16 + ln) * 136 + ks * 32 + qd * 8];
#pragma unroll
        for (int ti = 0; ti < 2; ++ti)
          acc1[ti][tjj] =
              __builtin_amdgcn_mfma_f32_16x16x32_bf16(afp[ti][ks], bf, acc1[ti][tjj], 0, 0, 0);
      }
    __syncthreads();  // all sB reads done -> next stage safe
    // ---- P-write (disjoint from sB; visible at pre-p2 barrier) ----
#pragma unroll
    for (int ti = 0; ti < 2; ++ti) {
      int cbase = 16 * ti + qd * 4;
      int cb = cbase >> 3;
#pragma unroll
      for (int tjj = 0; tjj < 4; ++tjj) {
        int d = 16 * (tjj & 1) + ln;
        int p = ww * 4 + 2 * (q & 1) + (tjj >> 1);  // pair = i_loc*4 + tile-local j
        uint2 u;
        u.x = pack_bf2(acc1[ti][tjj][0], acc1[ti][tjj][1]);
        u.y = pack_bf2(acc1[ti][tjj][2], acc1[ti][tjj][3]);
        *(uint2*)&sP[p * 1032 + d * 32 + ((((d >> 1) & 3) ^ cb) * 8) + (cbase & 7)] = u;
      }
    }
  }
  __syncthreads();  // all P-writes visible

  // ---- p2: operand-swapped mfma(W, P), each WF fragment applied to BOTH buffers ----
  f32x4 acc2[2][2][2];  // [tb][h2][mt]
#pragma unroll
  for (int a = 0; a < 2; ++a)
#pragma unroll
    for (int b = 0; b < 2; ++b)
#pragma unroll
      for (int c = 0; c < 2; ++c) acc2[a][b][c] = (f32x4){0.f, 0.f, 0.f, 0.f};
#pragma unroll
  for (int cc = 0; cc < 16; ++cc) {
    int ks = kq * 16 + cc;
    int swz = ((((ks >> 1) & 3) ^ qd) * 8);
    short8 afr[2][2];  // [tb][mt]
#pragma unroll
    for (int mt = 0; mt < 2; ++mt) {
      afr[0][mt] = *(const short8*)&sPA[(mt * 16 + ln) * 1032 + ks * 32 + swz];
      afr[1][mt] = *(const short8*)&sPB[(mt * 16 + ln) * 1032 + ks * 32 + swz];
    }
#pragma unroll
    for (int h2 = 0; h2 < 2; ++h2) {
      int zt = ztp * 2 + h2;
      short8 bfr = *(const short8*)(WF + ((size_t)(zt * 32 + ks) * 64 + lane) * 8);
#pragma unroll
      for (int tb = 0; tb < 2; ++tb)
#pragma unroll
        for (int mt = 0; mt < 2; ++mt)  // SWAPPED: D[m=z][n=p]
          acc2[tb][h2][mt] = __builtin_amdgcn_mfma_f32_16x16x32_bf16(bfr, afr[tb][mt],
                                                                    acc2[tb][h2][mt], 0, 0, 0);
    }
  }
  __syncthreads();  // all sP reads done -> redR overlay safe

  // ---- kq 2-way reduction via lane-linear redR slots (32 x 1KB) ----
  if (kq == 1) {
#pragma unroll
    for (int tb = 0; tb < 2; ++tb)
#pragma unroll
      for (int h2 = 0; h2 < 2; ++h2)
#pragma unroll
        for (int mt = 0; mt < 2; ++mt)
          *(f32x4*)&redR[((((tb * 4 + ztp) * 2 + h2) * 2 + mt) << 8) + lane * 4] =
              acc2[tb][h2][mt];
  }
  __syncthreads();
  if (kq == 0) {
#pragma unroll
    for (int tb = 0; tb < 2; ++tb)
#pragma unroll
      for (int h2 = 0; h2 < 2; ++h2) {
        int z = (ztp * 2 + h2) * 16 + qd * 4;
        f32x4 bz = *(const f32x4*)(bout + z);
#pragma unroll
        for (int mt = 0; mt < 2; ++mt) {
          int p = mt * 16 + ln;
          f32x4 v = acc2[tb][h2][mt] +
                    *(const f32x4*)&redR[((((tb * 4 + ztp) * 2 + h2) * 2 + mt) << 8) + lane * 4] +
                    bz;
          int i = i0 + (p >> 2), j = jg * 8 + tb * 4 + (p & 3);
          *(f32x4*)&out[((size_t)i * IDIM + j) * CZ + z] = v;
        }
      }
  }
}

extern "C" void kernel_launch(void* const* d_in, const int* in_sizes, int n_in,
                              void* d_out, int out_size, void* d_ws, size_t ws_size,
                              hipStream_t stream) {
  const float* msa = (const float*)d_in[0];
  const float* lnw = (const float*)d_in[1];
  const float* lnb = (const float*)d_in[2];
  const float* wl  = (const float*)d_in[3];
  const float* bl  = (const float*)d_in[4];
  const float* wr  = (const float*)d_in[5];
  const float* br  = (const float*)d_in[6];
  const float* wo  = (const float*)d_in[7];
  const float* bo  = (const float*)d_in[8];
  float* out = (float*)d_out;

  char* ws = (char*)d_ws;
  unsigned short* A2    = (unsigned short*)ws;                         // 2 MB (frag-major)
  unsigned short* Bbuf  = (unsigned short*)(ws + (2u << 20));          // 2 MB (row-major)
  unsigned short* wlrT2 = (unsigned short*)(ws + (4u << 20));          // 32 KB (frag-major)
  unsigned short* WF    = (unsigned short*)(ws + (4u << 20) + 32768);  // 256 KB

  (void)hipFuncSetAttribute((const void*)k_main,
                            hipFuncAttributeMaxDynamicSharedMemorySize, 149504);

  k_prep<<<72, 256, 0, stream>>>(wl, wr, wo, wlrT2, WF);
  k_lnproj<<<dim3(256, 2), 512, 0, stream>>>(msa, lnw, lnb, bl, br, wlrT2, A2, Bbuf);
  k_main<<<1024, 512, 149504, stream>>>(A2, Bbuf, WF, bo, out);
}

// Round 7
// 142.967 us; speedup vs baseline: 1.0107x; 1.0107x over previous
//
#include <hip/hip_runtime.h>

typedef __attribute__((ext_vector_type(8))) short short8;
typedef __attribute__((ext_vector_type(4))) float f32x4;

#define CM 256
#define CC 32
#define CZ 128
#define SDIM 128
#define IDIM 256

__device__ __forceinline__ unsigned short f2bf(float f) {
  union { float f; unsigned u; } v; v.f = f;
  unsigned r = v.u + 0x7fffu + ((v.u >> 16) & 1u);
  return (unsigned short)(r >> 16);
}
// pack two f32 -> two bf16 (round-half-up)
__device__ __forceinline__ unsigned pack_bf2(float a, float b) {
  union { float f; unsigned u; } x, y; x.f = a; y.f = b;
  return ((x.u + 0x8000u) >> 16) | ((y.u + 0x8000u) & 0xffff0000u);
}

// ---------------- kernel 0: weight prep ---------------- (unchanged)
__global__ void k_prep(const float* __restrict__ wl, const float* __restrict__ wr,
                       const float* __restrict__ wo,
                       unsigned short* __restrict__ wlrT2, unsigned short* __restrict__ WF) {
  int t = blockIdx.x * 256 + threadIdx.x;
  if (t < 2048) {
    int frag = t >> 6, lane = t & 63;
    int nt = frag >> 3, ks = frag & 7;
    int ln = lane & 15, qd = lane >> 4;
    int c64 = nt * 16 + ln;
#pragma unroll
    for (int e = 0; e < 8; ++e) {
      int cm = ks * 32 + qd * 8 + e;
      float v = (c64 < CC) ? wl[cm * CC + c64] : wr[cm * CC + (c64 - CC)];
      wlrT2[(size_t)t * 8 + e] = f2bf(v);
    }
  } else {
    int t2 = t - 2048;
    if (t2 < 8 * 32 * 64) {
      int zt = t2 >> 11, ks = (t2 >> 6) & 31, lane = t2 & 63;
      int ln = lane & 15, qd = lane >> 4;
      int z = zt * 16 + ln;
#pragma unroll
      for (int e = 0; e < 8; ++e) {
        int c = qd * 8 + e, d = ks;
        WF[(size_t)t2 * 8 + e] = f2bf(wo[(c * 32 + d) * CZ + z] * (1.0f / 128.0f));
      }
    }
  }
}

// ---------------- kernel 1 (v2): LayerNorm + dual projection, 8 waves ---------------- (r6)
__global__ __launch_bounds__(512) void k_lnproj(
    const float* __restrict__ x, const float* __restrict__ lnw, const float* __restrict__ lnb,
    const float* __restrict__ bl, const float* __restrict__ br,
    const unsigned short* __restrict__ wlrT2,
    unsigned short* __restrict__ A2, unsigned short* __restrict__ Bbuf) {
  __shared__ __align__(16) unsigned short xn[64][264];
  __shared__ __align__(16) unsigned short sT[64][72];
  int tid = threadIdx.x;
  int lane = tid & 63, ww = tid >> 6;      // 8 waves
  int qd = lane >> 4, ln = lane & 15;
  int i = blockIdx.x, sh = blockIdx.y;

  float4 w4 = ((const float4*)lnw)[lane];
  float4 b4 = ((const float4*)lnb)[lane];

#pragma unroll
  for (int rr = 0; rr < 8; ++rr) {
    int sl = ww * 8 + rr;
    int s = sh * 64 + sl;
    float4 v = ((const float4*)(x + ((size_t)s * IDIM + i) * CM))[lane];
    float s1 = v.x + v.y + v.z + v.w;
    float s2 = v.x * v.x + v.y * v.y + v.z * v.z + v.w * v.w;
#pragma unroll
    for (int off = 32; off; off >>= 1) {
      s1 += __shfl_xor(s1, off);
      s2 += __shfl_xor(s2, off);
    }
    float mu = s1 * (1.0f / 256.0f);
    float var = s2 * (1.0f / 256.0f) - mu * mu;
    float rs = rsqrtf(var + 1e-5f);
    ushort4 h;
    h.x = f2bf((v.x - mu) * rs * w4.x + b4.x);
    h.y = f2bf((v.y - mu) * rs * w4.y + b4.y);
    h.z = f2bf((v.z - mu) * rs * w4.z + b4.z);
    h.w = f2bf((v.w - mu) * rs * w4.w + b4.w);
    *(ushort4*)&xn[sl][lane * 4] = h;
  }
  __syncthreads();

  int mt = ww >> 1, nh = ww & 1;
  f32x4 acc[2];
#pragma unroll
  for (int t = 0; t < 2; ++t) acc[t] = (f32x4){0.f, 0.f, 0.f, 0.f};
#pragma unroll
  for (int ks = 0; ks < 8; ++ks) {
    short8 af = *(const short8*)&xn[mt * 16 + ln][ks * 32 + qd * 8];
#pragma unroll
    for (int t = 0; t < 2; ++t) {
      int nt = nh * 2 + t;
      short8 bf = *(const short8*)(wlrT2 + ((size_t)((nt * 8 + ks) * 64 + lane)) * 8);
      acc[t] = __builtin_amdgcn_mfma_f32_16x16x32_bf16(af, bf, acc[t], 0, 0, 0);
    }
  }
#pragma unroll
  for (int t = 0; t < 2; ++t) {
    int nt = nh * 2 + t;
    int c64 = nt * 16 + ln;
    float bias = (c64 < CC) ? bl[c64] : br[c64 - CC];
    ushort4 h;
    h.x = f2bf(acc[t][0] + bias);
    h.y = f2bf(acc[t][1] + bias);
    h.z = f2bf(acc[t][2] + bias);
    h.w = f2bf(acc[t][3] + bias);
    *(ushort4*)&sT[c64][mt * 16 + qd * 4] = h;
  }
  __syncthreads();

  if (ww < 4) {
    int rtloc = ww >> 1, ksl = ww & 1;
    short8 v = *(const short8*)&sT[rtloc * 16 + ln][ksl * 32 + qd * 8];
    *(short8*)(A2 + ((size_t)(((2 * i + rtloc) * 4 + (sh * 2 + ksl)) * 64 + lane)) * 8) = v;
  } else {
    int t2 = tid - 256;
    int row = t2 >> 3, ch = t2 & 7;
    short8 v = *(const short8*)&sT[CC + row][ch * 8];
    *(short8*)(Bbuf + ((size_t)(i * CC + row)) * SDIM + sh * 64 + ch * 8) = v;
  }
}

// ---------------- kernel 2 (v7): 32-pair blocks, 2 blocks/CU, pinned-A, setprio ----
// Merge of r2 (co-residency wins) and r5 (pinned-A, prefetch). 2048 blocks x 512 thr
// (8 waves). Block = i0(8 i) x 4 j = 32 pairs. LDS = 74,752 B -> 2 blocks/CU resident
// (2 x 74,752 <= 163,840): one block's p2 (L2-heavy WF stream) overlaps the other's
// p1 (LDS/MFMA heavy) -- attacking the measured ~1.0 overlap factor of the phased
// pipes. T5 setprio(1) wraps both MFMA clusters: with two INDEPENDENT co-resident
// blocks the CU scheduler has role diversity to arbitrate (m191 regime, not m190's
// lockstep null).
// LDS: sP [32][1032] sh = 66,048 @ 0; sB [32][136] sh = 8,704 @ 66,048.
//      redR 16 KB f32 overlays sP rows 0..7 AFTER the post-p2 barrier.
// Per q (q = jloc 0..3): {stage sB(32 B-rows = j q), bar, issue bpre(q+1), p1-pass
// (setprio-wrapped), bar, P-write}. Then pre-p2 bar, p2 (setprio-wrapped), post-p2
// bar, 2-way kq reduction, store.
// Per-wave regs: afp 32 + bpre 4 + acc 16+16 (AGPR) + temps -> ~60-70 VGPR, under the
// 128 cap at 4 waves/SIMD (v6 measured 56 with the same shape).
__global__ __launch_bounds__(512, 2) void k_main(
    const unsigned short* __restrict__ A2, const unsigned short* __restrict__ Bbuf,
    const unsigned short* __restrict__ WF, const float* __restrict__ bout,
    float* __restrict__ out) {
  extern __shared__ __align__(16) char lds[];
  unsigned short* sP = (unsigned short*)lds;             // [32][1032]
  unsigned short* sB = (unsigned short*)(lds + 66048);   // [32][136]
  float* redR = (float*)lds;                             // 16 slots x 1 KB (post-p2)
  int tid = threadIdx.x;
  int lane = tid & 63, ww = tid >> 6;  // 8 waves
  int qd = lane >> 4, ln = lane & 15;
  int bx = blockIdx.x;
  int itile = (bx & 7) * 4 + ((bx >> 3) & 3);  // XCD-affine i-tile (0..31)
  int jg = bx >> 5;                            // j-group (0..63): j = jg*4 + q
  int i0 = itile * 8;
  int ztp = ww & 3, kq = ww >> 2;              // p2 wave coords (4 x 2)

  // ---- pinned A-fragments: wave ww owns P-row-tiles rt = i0*2 + ww*2 + ti ----
  short8 afp[2][4];  // [ti][ks] = 8 frags = 32 VGPR
#pragma unroll
  for (int ti = 0; ti < 2; ++ti)
#pragma unroll
    for (int ks = 0; ks < 4; ++ks)
      afp[ti][ks] =
          *(const short8*)(A2 + ((size_t)((i0 * 2 + ww * 2 + ti) * 4 + ks) * 64 + lane) * 8);

  // ---- prologue: issue B(q=0) load (32 rows x 16 chunks = 512 units, 1/thread) ----
  short8 bpre;
  {
    int r = tid >> 4, ch = tid & 15;
    bpre = *(const short8*)(Bbuf + ((size_t)(jg * 4) * CC + r) * SDIM + ch * 8);
  }

#pragma unroll
  for (int q = 0; q < 4; ++q) {
    // ---- stage B(q): 1 j-col's 32 d-rows ----
    {
      int r = tid >> 4, ch = tid & 15;
      *(short8*)&sB[r * 136 + ch * 8] = bpre;
    }
    __syncthreads();
    // ---- issue B(q+1) load (hidden under p1) ----
    if (q < 3) {
      int r = tid >> 4, ch = tid & 15;
      bpre = *(const short8*)(Bbuf + ((size_t)(jg * 4 + q + 1) * CC + r) * SDIM + ch * 8);
    }
    // ---- p1 pass: P[wave's 32 A-rows][32 d-cols of j=q] ----
    f32x4 acc1[2][2];  // [ti][tjj]
#pragma unroll
    for (int a = 0; a < 2; ++a)
#pragma unroll
      for (int b = 0; b < 2; ++b) acc1[a][b] = (f32x4){0.f, 0.f, 0.f, 0.f};
    __builtin_amdgcn_s_setprio(1);
#pragma unroll
    for (int ks = 0; ks < 4; ++ks)
#pragma unroll
      for (int tjj = 0; tjj < 2; ++tjj) {
        short8 bf = *(const short8*)&sB[(tjj * 16 + ln) * 136 + ks * 32 + qd * 8];
#pragma unroll
        for (int ti = 0; ti < 2; ++ti)
          acc1[ti][tjj] =
              __builtin_amdgcn_mfma_f32_16x16x32_bf16(afp[ti][ks], bf, acc1[ti][tjj], 0, 0, 0);
      }
    __builtin_amdgcn_s_setprio(0);
    __syncthreads();  // all sB reads done -> next q's stage safe
    // ---- P-write: p = ww*4 + q (wave-uniform); swizzled kappa slots ----
#pragma unroll
    for (int ti = 0; ti < 2; ++ti) {
      int cbase = 16 * ti + qd * 4;
      int cb = cbase >> 3;
#pragma unroll
      for (int tjj = 0; tjj < 2; ++tjj) {
        int d = 16 * tjj + ln;
        int p = ww * 4 + q;
        uint2 u;
        u.x = pack_bf2(acc1[ti][tjj][0], acc1[ti][tjj][1]);
        u.y = pack_bf2(acc1[ti][tjj][2], acc1[ti][tjj][3]);
        *(uint2*)&sP[p * 1032 + d * 32 + ((((d >> 1) & 3) ^ cb) * 8) + (cbase & 7)] = u;
      }
    }
  }
  __syncthreads();  // all P-writes visible

  // ---- p2: operand-swapped mfma(W, P); WF streamed from L2 ----
  f32x4 acc2[2][2];  // [h2][mt]
#pragma unroll
  for (int a = 0; a < 2; ++a)
#pragma unroll
    for (int b = 0; b < 2; ++b) acc2[a][b] = (f32x4){0.f, 0.f, 0.f, 0.f};
  __builtin_amdgcn_s_setprio(1);
#pragma unroll
  for (int cc = 0; cc < 16; ++cc) {
    int ks = kq * 16 + cc;
    int swz = ((((ks >> 1) & 3) ^ qd) * 8);
    short8 afr[2];  // [mt]
#pragma unroll
    for (int mt = 0; mt < 2; ++mt)
      afr[mt] = *(const short8*)&sP[(mt * 16 + ln) * 1032 + ks * 32 + swz];
#pragma unroll
    for (int h2 = 0; h2 < 2; ++h2) {
      int zt = ztp * 2 + h2;
      short8 bfr = *(const short8*)(WF + ((size_t)(zt * 32 + ks) * 64 + lane) * 8);
#pragma unroll
      for (int mt = 0; mt < 2; ++mt)  // SWAPPED: D[m=z][n=p]
        acc2[h2][mt] =
            __builtin_amdgcn_mfma_f32_16x16x32_bf16(bfr, afr[mt], acc2[h2][mt], 0, 0, 0);
    }
  }
  __builtin_amdgcn_s_setprio(0);
  __syncthreads();  // all sP reads done -> redR overlay safe

  // ---- kq 2-way reduction via lane-linear redR slots (16 x 1KB) ----
  if (kq == 1) {
#pragma unroll
    for (int h2 = 0; h2 < 2; ++h2)
#pragma unroll
      for (int mt = 0; mt < 2; ++mt)
        *(f32x4*)&redR[(((ztp * 2 + h2) * 2 + mt) << 8) + lane * 4] = acc2[h2][mt];
  }
  __syncthreads();
  if (kq == 0) {
#pragma unroll
    for (int h2 = 0; h2 < 2; ++h2) {
      int z = (ztp * 2 + h2) * 16 + qd * 4;
      f32x4 bz = *(const f32x4*)(bout + z);
#pragma unroll
      for (int mt = 0; mt < 2; ++mt) {
        int p = mt * 16 + ln;
        f32x4 v = acc2[h2][mt] +
                  *(const f32x4*)&redR[(((ztp * 2 + h2) * 2 + mt) << 8) + lane * 4] + bz;
        int i = i0 + (p >> 2), j = jg * 4 + (p & 3);
        *(f32x4*)&out[((size_t)i * IDIM + j) * CZ + z] = v;
      }
    }
  }
}

extern "C" void kernel_launch(void* const* d_in, const int* in_sizes, int n_in,
                              void* d_out, int out_size, void* d_ws, size_t ws_size,
                              hipStream_t stream) {
  const float* msa = (const float*)d_in[0];
  const float* lnw = (const float*)d_in[1];
  const float* lnb = (const float*)d_in[2];
  const float* wl  = (const float*)d_in[3];
  const float* bl  = (const float*)d_in[4];
  const float* wr  = (const float*)d_in[5];
  const float* br  = (const float*)d_in[6];
  const float* wo  = (const float*)d_in[7];
  const float* bo  = (const float*)d_in[8];
  float* out = (float*)d_out;

  char* ws = (char*)d_ws;
  unsigned short* A2    = (unsigned short*)ws;                         // 2 MB (frag-major)
  unsigned short* Bbuf  = (unsigned short*)(ws + (2u << 20));          // 2 MB (row-major)
  unsigned short* wlrT2 = (unsigned short*)(ws + (4u << 20));          // 32 KB (frag-major)
  unsigned short* WF    = (unsigned short*)(ws + (4u << 20) + 32768);  // 256 KB

  (void)hipFuncSetAttribute((const void*)k_main,
                            hipFuncAttributeMaxDynamicSharedMemorySize, 74752);

  k_prep<<<72, 256, 0, stream>>>(wl, wr, wo, wlrT2, WF);
  k_lnproj<<<dim3(256, 2), 512, 0, stream>>>(msa, lnw, lnb, bl, br, wlrT2, A2, Bbuf);
  k_main<<<2048, 512, 74752, stream>>>(A2, Bbuf, WF, bo, out);
}

// Round 8
// 142.467 us; speedup vs baseline: 1.0142x; 1.0035x over previous
//
#include <hip/hip_runtime.h>

typedef __attribute__((ext_vector_type(8))) short short8;
typedef __attribute__((ext_vector_type(4))) float f32x4;

#define CM 256
#define CC 32
#define CZ 128
#define SDIM 128
#define IDIM 256

__device__ __forceinline__ unsigned short f2bf(float f) {
  union { float f; unsigned u; } v; v.f = f;
  unsigned r = v.u + 0x7fffu + ((v.u >> 16) & 1u);
  return (unsigned short)(r >> 16);
}
// pack two f32 -> two bf16 (round-half-up)
__device__ __forceinline__ unsigned pack_bf2(float a, float b) {
  union { float f; unsigned u; } x, y; x.f = a; y.f = b;
  return ((x.u + 0x8000u) >> 16) | ((y.u + 0x8000u) & 0xffff0000u);
}

// ---------------- kernel 0: weight prep ---------------- (unchanged)
__global__ void k_prep(const float* __restrict__ wl, const float* __restrict__ wr,
                       const float* __restrict__ wo,
                       unsigned short* __restrict__ wlrT2, unsigned short* __restrict__ WF) {
  int t = blockIdx.x * 256 + threadIdx.x;
  if (t < 2048) {
    int frag = t >> 6, lane = t & 63;
    int nt = frag >> 3, ks = frag & 7;
    int ln = lane & 15, qd = lane >> 4;
    int c64 = nt * 16 + ln;
#pragma unroll
    for (int e = 0; e < 8; ++e) {
      int cm = ks * 32 + qd * 8 + e;
      float v = (c64 < CC) ? wl[cm * CC + c64] : wr[cm * CC + (c64 - CC)];
      wlrT2[(size_t)t * 8 + e] = f2bf(v);
    }
  } else {
    int t2 = t - 2048;
    if (t2 < 8 * 32 * 64) {
      int zt = t2 >> 11, ks = (t2 >> 6) & 31, lane = t2 & 63;
      int ln = lane & 15, qd = lane >> 4;
      int z = zt * 16 + ln;
#pragma unroll
      for (int e = 0; e < 8; ++e) {
        int c = qd * 8 + e, d = ks;
        WF[(size_t)t2 * 8 + e] = f2bf(wo[(c * 32 + d) * CZ + z] * (1.0f / 128.0f));
      }
    }
  }
}

// ---------------- kernel 1 (v2): LayerNorm + dual projection, 8 waves ---------------- (r6)
__global__ __launch_bounds__(512) void k_lnproj(
    const float* __restrict__ x, const float* __restrict__ lnw, const float* __restrict__ lnb,
    const float* __restrict__ bl, const float* __restrict__ br,
    const unsigned short* __restrict__ wlrT2,
    unsigned short* __restrict__ A2, unsigned short* __restrict__ Bbuf) {
  __shared__ __align__(16) unsigned short xn[64][264];
  __shared__ __align__(16) unsigned short sT[64][72];
  int tid = threadIdx.x;
  int lane = tid & 63, ww = tid >> 6;      // 8 waves
  int qd = lane >> 4, ln = lane & 15;
  int i = blockIdx.x, sh = blockIdx.y;

  float4 w4 = ((const float4*)lnw)[lane];
  float4 b4 = ((const float4*)lnb)[lane];

#pragma unroll
  for (int rr = 0; rr < 8; ++rr) {
    int sl = ww * 8 + rr;
    int s = sh * 64 + sl;
    float4 v = ((const float4*)(x + ((size_t)s * IDIM + i) * CM))[lane];
    float s1 = v.x + v.y + v.z + v.w;
    float s2 = v.x * v.x + v.y * v.y + v.z * v.z + v.w * v.w;
#pragma unroll
    for (int off = 32; off; off >>= 1) {
      s1 += __shfl_xor(s1, off);
      s2 += __shfl_xor(s2, off);
    }
    float mu = s1 * (1.0f / 256.0f);
    float var = s2 * (1.0f / 256.0f) - mu * mu;
    float rs = rsqrtf(var + 1e-5f);
    ushort4 h;
    h.x = f2bf((v.x - mu) * rs * w4.x + b4.x);
    h.y = f2bf((v.y - mu) * rs * w4.y + b4.y);
    h.z = f2bf((v.z - mu) * rs * w4.z + b4.z);
    h.w = f2bf((v.w - mu) * rs * w4.w + b4.w);
    *(ushort4*)&xn[sl][lane * 4] = h;
  }
  __syncthreads();

  int mt = ww >> 1, nh = ww & 1;
  f32x4 acc[2];
#pragma unroll
  for (int t = 0; t < 2; ++t) acc[t] = (f32x4){0.f, 0.f, 0.f, 0.f};
#pragma unroll
  for (int ks = 0; ks < 8; ++ks) {
    short8 af = *(const short8*)&xn[mt * 16 + ln][ks * 32 + qd * 8];
#pragma unroll
    for (int t = 0; t < 2; ++t) {
      int nt = nh * 2 + t;
      short8 bf = *(const short8*)(wlrT2 + ((size_t)((nt * 8 + ks) * 64 + lane)) * 8);
      acc[t] = __builtin_amdgcn_mfma_f32_16x16x32_bf16(af, bf, acc[t], 0, 0, 0);
    }
  }
#pragma unroll
  for (int t = 0; t < 2; ++t) {
    int nt = nh * 2 + t;
    int c64 = nt * 16 + ln;
    float bias = (c64 < CC) ? bl[c64] : br[c64 - CC];
    ushort4 h;
    h.x = f2bf(acc[t][0] + bias);
    h.y = f2bf(acc[t][1] + bias);
    h.z = f2bf(acc[t][2] + bias);
    h.w = f2bf(acc[t][3] + bias);
    *(ushort4*)&sT[c64][mt * 16 + qd * 4] = h;
  }
  __syncthreads();

  if (ww < 4) {
    int rtloc = ww >> 1, ksl = ww & 1;
    short8 v = *(const short8*)&sT[rtloc * 16 + ln][ksl * 32 + qd * 8];
    *(short8*)(A2 + ((size_t)(((2 * i + rtloc) * 4 + (sh * 2 + ksl)) * 64 + lane)) * 8) = v;
  } else {
    int t2 = tid - 256;
    int row = t2 >> 3, ch = t2 & 7;
    short8 v = *(const short8*)&sT[CC + row][ch * 8];
    *(short8*)(Bbuf + ((size_t)(i * CC + row)) * SDIM + sh * 64 + ch * 8) = v;
  }
}

// ---------------- kernel 2 (v8): r7 + full latency pipelining ----
// Identical tiling/phases to r7 (32-pair blocks, 2 blocks/CU, pinned-A, setprio),
// plus three latency fixes:
//   1. bpre[4]: ALL four B-tile loads issued at the PROLOGUE (the 3 recurring
//      ~600-900cy vmcnt stalls at stage(q>0) disappear; stage = bare ds_write).
//   2. wpre[4][2]: first 4 cc x 2 zt WF fragments loaded BEFORE the pre-p2 barrier
//      (compiler cannot hoist global loads across __syncthreads itself) -> p2's
//      L2 stream starts a phase early (T14).
//   3. q=3's post-p1 barrier dropped (no later sB stage; pre-p2 barrier covers
//      P-write visibility). 8 barriers/block.
// Regs: afp 32 + bpre 32 + acc 16 + temps -> ~90-100 VGPR (cap 128 at 4 w/SIMD);
// wpre 16 allocated after afp dies. LDS unchanged: 74,752 B -> 2 blocks/CU.
__global__ __launch_bounds__(512, 2) void k_main(
    const unsigned short* __restrict__ A2, const unsigned short* __restrict__ Bbuf,
    const unsigned short* __restrict__ WF, const float* __restrict__ bout,
    float* __restrict__ out) {
  extern __shared__ __align__(16) char lds[];
  unsigned short* sP = (unsigned short*)lds;             // [32][1032]
  unsigned short* sB = (unsigned short*)(lds + 66048);   // [32][136]
  float* redR = (float*)lds;                             // 16 slots x 1 KB (post-p2)
  int tid = threadIdx.x;
  int lane = tid & 63, ww = tid >> 6;  // 8 waves
  int qd = lane >> 4, ln = lane & 15;
  int bx = blockIdx.x;
  int itile = (bx & 7) * 4 + ((bx >> 3) & 3);  // XCD-affine i-tile (0..31)
  int jg = bx >> 5;                            // j-group (0..63): j = jg*4 + q
  int i0 = itile * 8;
  int ztp = ww & 3, kq = ww >> 2;              // p2 wave coords (4 x 2)

  // ---- prologue: issue ALL B loads + pinned A loads up front ----
  short8 bpre[4];
  {
    int r = tid >> 4, ch = tid & 15;
#pragma unroll
    for (int q = 0; q < 4; ++q)
      bpre[q] = *(const short8*)(Bbuf + ((size_t)(jg * 4 + q) * CC + r) * SDIM + ch * 8);
  }
  short8 afp[2][4];  // [ti][ks] = 8 frags = 32 VGPR
#pragma unroll
  for (int ti = 0; ti < 2; ++ti)
#pragma unroll
    for (int ks = 0; ks < 4; ++ks)
      afp[ti][ks] =
          *(const short8*)(A2 + ((size_t)((i0 * 2 + ww * 2 + ti) * 4 + ks) * 64 + lane) * 8);

#pragma unroll
  for (int q = 0; q < 4; ++q) {
    // ---- stage B(q): bare ds_write (load already in flight/landed) ----
    {
      int r = tid >> 4, ch = tid & 15;
      *(short8*)&sB[r * 136 + ch * 8] = bpre[q];
    }
    __syncthreads();
    // ---- p1 pass: P[wave's 32 A-rows][32 d-cols of j=q] ----
    f32x4 acc1[2][2];  // [ti][tjj]
#pragma unroll
    for (int a = 0; a < 2; ++a)
#pragma unroll
      for (int b = 0; b < 2; ++b) acc1[a][b] = (f32x4){0.f, 0.f, 0.f, 0.f};
    __builtin_amdgcn_s_setprio(1);
#pragma unroll
    for (int ks = 0; ks < 4; ++ks)
#pragma unroll
      for (int tjj = 0; tjj < 2; ++tjj) {
        short8 bf = *(const short8*)&sB[(tjj * 16 + ln) * 136 + ks * 32 + qd * 8];
#pragma unroll
        for (int ti = 0; ti < 2; ++ti)
          acc1[ti][tjj] =
              __builtin_amdgcn_mfma_f32_16x16x32_bf16(afp[ti][ks], bf, acc1[ti][tjj], 0, 0, 0);
      }
    __builtin_amdgcn_s_setprio(0);
    if (q < 3) __syncthreads();  // sB reads done before next stage; q=3: pre-p2 bar covers
    // ---- P-write: p = ww*4 + q (wave-uniform); swizzled kappa slots ----
#pragma unroll
    for (int ti = 0; ti < 2; ++ti) {
      int cbase = 16 * ti + qd * 4;
      int cb = cbase >> 3;
#pragma unroll
      for (int tjj = 0; tjj < 2; ++tjj) {
        int d = 16 * tjj + ln;
        int p = ww * 4 + q;
        uint2 u;
        u.x = pack_bf2(acc1[ti][tjj][0], acc1[ti][tjj][1]);
        u.y = pack_bf2(acc1[ti][tjj][2], acc1[ti][tjj][3]);
        *(uint2*)&sP[p * 1032 + d * 32 + ((((d >> 1) & 3) ^ cb) * 8) + (cbase & 7)] = u;
      }
    }
  }

  // ---- WF head-hoist: issue first 4 cc x 2 zt fragment loads BEFORE the barrier ----
  short8 wpre[4][2];
#pragma unroll
  for (int cc = 0; cc < 4; ++cc)
#pragma unroll
    for (int h2 = 0; h2 < 2; ++h2)
      wpre[cc][h2] = *(const short8*)(
          WF + ((size_t)((ztp * 2 + h2) * 32 + kq * 16 + cc) * 64 + lane) * 8);

  __syncthreads();  // all P-writes visible

  // ---- p2: operand-swapped mfma(W, P); WF streamed from L2 ----
  f32x4 acc2[2][2];  // [h2][mt]
#pragma unroll
  for (int a = 0; a < 2; ++a)
#pragma unroll
    for (int b = 0; b < 2; ++b) acc2[a][b] = (f32x4){0.f, 0.f, 0.f, 0.f};
  __builtin_amdgcn_s_setprio(1);
#pragma unroll
  for (int cc = 0; cc < 16; ++cc) {
    int ks = kq * 16 + cc;
    int swz = ((((ks >> 1) & 3) ^ qd) * 8);
    short8 afr[2];  // [mt]
#pragma unroll
    for (int mt = 0; mt < 2; ++mt)
      afr[mt] = *(const short8*)&sP[(mt * 16 + ln) * 1032 + ks * 32 + swz];
#pragma unroll
    for (int h2 = 0; h2 < 2; ++h2) {
      int zt = ztp * 2 + h2;
      short8 bfr = (cc < 4) ? wpre[cc][h2]
                            : *(const short8*)(WF + ((size_t)(zt * 32 + ks) * 64 + lane) * 8);
#pragma unroll
      for (int mt = 0; mt < 2; ++mt)  // SWAPPED: D[m=z][n=p]
        acc2[h2][mt] =
            __builtin_amdgcn_mfma_f32_16x16x32_bf16(bfr, afr[mt], acc2[h2][mt], 0, 0, 0);
    }
  }
  __builtin_amdgcn_s_setprio(0);
  __syncthreads();  // all sP reads done -> redR overlay safe

  // ---- kq 2-way reduction via lane-linear redR slots (16 x 1KB) ----
  if (kq == 1) {
#pragma unroll
    for (int h2 = 0; h2 < 2; ++h2)
#pragma unroll
      for (int mt = 0; mt < 2; ++mt)
        *(f32x4*)&redR[(((ztp * 2 + h2) * 2 + mt) << 8) + lane * 4] = acc2[h2][mt];
  }
  __syncthreads();
  if (kq == 0) {
#pragma unroll
    for (int h2 = 0; h2 < 2; ++h2) {
      int z = (ztp * 2 + h2) * 16 + qd * 4;
      f32x4 bz = *(const f32x4*)(bout + z);
#pragma unroll
      for (int mt = 0; mt < 2; ++mt) {
        int p = mt * 16 + ln;
        f32x4 v = acc2[h2][mt] +
                  *(const f32x4*)&redR[(((ztp * 2 + h2) * 2 + mt) << 8) + lane * 4] + bz;
        int i = i0 + (p >> 2), j = jg * 4 + (p & 3);
        *(f32x4*)&out[((size_t)i * IDIM + j) * CZ + z] = v;
      }
    }
  }
}

extern "C" void kernel_launch(void* const* d_in, const int* in_sizes, int n_in,
                              void* d_out, int out_size, void* d_ws, size_t ws_size,
                              hipStream_t stream) {
  const float* msa = (const float*)d_in[0];
  const float* lnw = (const float*)d_in[1];
  const float* lnb = (const float*)d_in[2];
  const float* wl  = (const float*)d_in[3];
  const float* bl  = (const float*)d_in[4];
  const float* wr  = (const float*)d_in[5];
  const float* br  = (const float*)d_in[6];
  const float* wo  = (const float*)d_in[7];
  const float* bo  = (const float*)d_in[8];
  float* out = (float*)d_out;

  char* ws = (char*)d_ws;
  unsigned short* A2    = (unsigned short*)ws;                         // 2 MB (frag-major)
  unsigned short* Bbuf  = (unsigned short*)(ws + (2u << 20));          // 2 MB (row-major)
  unsigned short* wlrT2 = (unsigned short*)(ws + (4u << 20));          // 32 KB (frag-major)
  unsigned short* WF    = (unsigned short*)(ws + (4u << 20) + 32768);  // 256 KB

  (void)hipFuncSetAttribute((const void*)k_main,
                            hipFuncAttributeMaxDynamicSharedMemorySize, 74752);

  k_prep<<<72, 256, 0, stream>>>(wl, wr, wo, wlrT2, WF);
  k_lnproj<<<dim3(256, 2), 512, 0, stream>>>(msa, lnw, lnb, bl, br, wlrT2, A2, Bbuf);
  k_main<<<2048, 512, 74752, stream>>>(A2, Bbuf, WF, bo, out);
}

// Round 9
// 141.097 us; speedup vs baseline: 1.0241x; 1.0097x over previous
//
#include <hip/hip_runtime.h>

typedef __attribute__((ext_vector_type(8))) short short8;
typedef __attribute__((ext_vector_type(4))) float f32x4;

#define CM 256
#define CC 32
#define CZ 128
#define SDIM 128
#define IDIM 256

__device__ __forceinline__ unsigned short f2bf(float f) {
  union { float f; unsigned u; } v; v.f = f;
  unsigned r = v.u + 0x7fffu + ((v.u >> 16) & 1u);
  return (unsigned short)(r >> 16);
}
// pack two f32 -> two bf16 (round-half-up)
__device__ __forceinline__ unsigned pack_bf2(float a, float b) {
  union { float f; unsigned u; } x, y; x.f = a; y.f = b;
  return ((x.u + 0x8000u) >> 16) | ((y.u + 0x8000u) & 0xffff0000u);
}

// LDS-only barrier: wait local LDS ops, then raw s_barrier -- does NOT drain vmcnt,
// so global->register prefetches stay in flight across phases (T3/T4; m97-ceiling fix).
// Legal here because k_main's cross-wave visibility is LDS-only (loads target regs,
// not LDS; stores need no ordering). "memory" clobber stops compiler reordering.
__device__ __forceinline__ void bar_lds() {
  asm volatile("s_waitcnt lgkmcnt(0)" ::: "memory");
  __builtin_amdgcn_s_barrier();
}

// ---------------- kernel 0: weight prep ---------------- (unchanged)
__global__ void k_prep(const float* __restrict__ wl, const float* __restrict__ wr,
                       const float* __restrict__ wo,
                       unsigned short* __restrict__ wlrT2, unsigned short* __restrict__ WF) {
  int t = blockIdx.x * 256 + threadIdx.x;
  if (t < 2048) {
    int frag = t >> 6, lane = t & 63;
    int nt = frag >> 3, ks = frag & 7;
    int ln = lane & 15, qd = lane >> 4;
    int c64 = nt * 16 + ln;
#pragma unroll
    for (int e = 0; e < 8; ++e) {
      int cm = ks * 32 + qd * 8 + e;
      float v = (c64 < CC) ? wl[cm * CC + c64] : wr[cm * CC + (c64 - CC)];
      wlrT2[(size_t)t * 8 + e] = f2bf(v);
    }
  } else {
    int t2 = t - 2048;
    if (t2 < 8 * 32 * 64) {
      int zt = t2 >> 11, ks = (t2 >> 6) & 31, lane = t2 & 63;
      int ln = lane & 15, qd = lane >> 4;
      int z = zt * 16 + ln;
#pragma unroll
      for (int e = 0; e < 8; ++e) {
        int c = qd * 8 + e, d = ks;
        WF[(size_t)t2 * 8 + e] = f2bf(wo[(c * 32 + d) * CZ + z] * (1.0f / 128.0f));
      }
    }
  }
}

// ---------------- kernel 1 (v2): LayerNorm + dual projection, 8 waves ---------------- (r6)
__global__ __launch_bounds__(512) void k_lnproj(
    const float* __restrict__ x, const float* __restrict__ lnw, const float* __restrict__ lnb,
    const float* __restrict__ bl, const float* __restrict__ br,
    const unsigned short* __restrict__ wlrT2,
    unsigned short* __restrict__ A2, unsigned short* __restrict__ Bbuf) {
  __shared__ __align__(16) unsigned short xn[64][264];
  __shared__ __align__(16) unsigned short sT[64][72];
  int tid = threadIdx.x;
  int lane = tid & 63, ww = tid >> 6;      // 8 waves
  int qd = lane >> 4, ln = lane & 15;
  int i = blockIdx.x, sh = blockIdx.y;

  float4 w4 = ((const float4*)lnw)[lane];
  float4 b4 = ((const float4*)lnb)[lane];

#pragma unroll
  for (int rr = 0; rr < 8; ++rr) {
    int sl = ww * 8 + rr;
    int s = sh * 64 + sl;
    float4 v = ((const float4*)(x + ((size_t)s * IDIM + i) * CM))[lane];
    float s1 = v.x + v.y + v.z + v.w;
    float s2 = v.x * v.x + v.y * v.y + v.z * v.z + v.w * v.w;
#pragma unroll
    for (int off = 32; off; off >>= 1) {
      s1 += __shfl_xor(s1, off);
      s2 += __shfl_xor(s2, off);
    }
    float mu = s1 * (1.0f / 256.0f);
    float var = s2 * (1.0f / 256.0f) - mu * mu;
    float rs = rsqrtf(var + 1e-5f);
    ushort4 h;
    h.x = f2bf((v.x - mu) * rs * w4.x + b4.x);
    h.y = f2bf((v.y - mu) * rs * w4.y + b4.y);
    h.z = f2bf((v.z - mu) * rs * w4.z + b4.z);
    h.w = f2bf((v.w - mu) * rs * w4.w + b4.w);
    *(ushort4*)&xn[sl][lane * 4] = h;
  }
  __syncthreads();

  int mt = ww >> 1, nh = ww & 1;
  f32x4 acc[2];
#pragma unroll
  for (int t = 0; t < 2; ++t) acc[t] = (f32x4){0.f, 0.f, 0.f, 0.f};
#pragma unroll
  for (int ks = 0; ks < 8; ++ks) {
    short8 af = *(const short8*)&xn[mt * 16 + ln][ks * 32 + qd * 8];
#pragma unroll
    for (int t = 0; t < 2; ++t) {
      int nt = nh * 2 + t;
      short8 bf = *(const short8*)(wlrT2 + ((size_t)((nt * 8 + ks) * 64 + lane)) * 8);
      acc[t] = __builtin_amdgcn_mfma_f32_16x16x32_bf16(af, bf, acc[t], 0, 0, 0);
    }
  }
#pragma unroll
  for (int t = 0; t < 2; ++t) {
    int nt = nh * 2 + t;
    int c64 = nt * 16 + ln;
    float bias = (c64 < CC) ? bl[c64] : br[c64 - CC];
    ushort4 h;
    h.x = f2bf(acc[t][0] + bias);
    h.y = f2bf(acc[t][1] + bias);
    h.z = f2bf(acc[t][2] + bias);
    h.w = f2bf(acc[t][3] + bias);
    *(ushort4*)&sT[c64][mt * 16 + qd * 4] = h;
  }
  __syncthreads();

  if (ww < 4) {
    int rtloc = ww >> 1, ksl = ww & 1;
    short8 v = *(const short8*)&sT[rtloc * 16 + ln][ksl * 32 + qd * 8];
    *(short8*)(A2 + ((size_t)(((2 * i + rtloc) * 4 + (sh * 2 + ksl)) * 64 + lane)) * 8) = v;
  } else {
    int t2 = tid - 256;
    int row = t2 >> 3, ch = t2 & 7;
    short8 v = *(const short8*)&sT[CC + row][ch * 8];
    *(short8*)(Bbuf + ((size_t)(i * CC + row)) * SDIM + sh * 64 + ch * 8) = v;
  }
}

// ---------------- kernel 2 (v9): r8 + LDS-only barriers (counted-vmcnt pipeline) ----
// BYTE-IDENTICAL to r8 except all 10 __syncthreads() -> bar_lds(). r8's prologue
// preload (bpre[4]+afp[8]) and wpre head-hoist now actually stay in flight: the
// compiler emits COUNTED vmcnt at each register use instead of vmcnt(0) drains at
// every barrier (which is what nullified r8's pipelining). Single-mechanism A/B.
__global__ __launch_bounds__(512, 2) void k_main(
    const unsigned short* __restrict__ A2, const unsigned short* __restrict__ Bbuf,
    const unsigned short* __restrict__ WF, const float* __restrict__ bout,
    float* __restrict__ out) {
  extern __shared__ __align__(16) char lds[];
  unsigned short* sP = (unsigned short*)lds;             // [32][1032]
  unsigned short* sB = (unsigned short*)(lds + 66048);   // [32][136]
  float* redR = (float*)lds;                             // 16 slots x 1 KB (post-p2)
  int tid = threadIdx.x;
  int lane = tid & 63, ww = tid >> 6;  // 8 waves
  int qd = lane >> 4, ln = lane & 15;
  int bx = blockIdx.x;
  int itile = (bx & 7) * 4 + ((bx >> 3) & 3);  // XCD-affine i-tile (0..31)
  int jg = bx >> 5;                            // j-group (0..63): j = jg*4 + q
  int i0 = itile * 8;
  int ztp = ww & 3, kq = ww >> 2;              // p2 wave coords (4 x 2)

  // ---- prologue: issue ALL B loads + pinned A loads up front ----
  short8 bpre[4];
  {
    int r = tid >> 4, ch = tid & 15;
#pragma unroll
    for (int q = 0; q < 4; ++q)
      bpre[q] = *(const short8*)(Bbuf + ((size_t)(jg * 4 + q) * CC + r) * SDIM + ch * 8);
  }
  short8 afp[2][4];  // [ti][ks] = 8 frags = 32 VGPR
#pragma unroll
  for (int ti = 0; ti < 2; ++ti)
#pragma unroll
    for (int ks = 0; ks < 4; ++ks)
      afp[ti][ks] =
          *(const short8*)(A2 + ((size_t)((i0 * 2 + ww * 2 + ti) * 4 + ks) * 64 + lane) * 8);

#pragma unroll
  for (int q = 0; q < 4; ++q) {
    // ---- stage B(q): bare ds_write (load waited via counted vmcnt at use) ----
    {
      int r = tid >> 4, ch = tid & 15;
      *(short8*)&sB[r * 136 + ch * 8] = bpre[q];
    }
    bar_lds();
    // ---- p1 pass: P[wave's 32 A-rows][32 d-cols of j=q] ----
    f32x4 acc1[2][2];  // [ti][tjj]
#pragma unroll
    for (int a = 0; a < 2; ++a)
#pragma unroll
      for (int b = 0; b < 2; ++b) acc1[a][b] = (f32x4){0.f, 0.f, 0.f, 0.f};
    __builtin_amdgcn_s_setprio(1);
#pragma unroll
    for (int ks = 0; ks < 4; ++ks)
#pragma unroll
      for (int tjj = 0; tjj < 2; ++tjj) {
        short8 bf = *(const short8*)&sB[(tjj * 16 + ln) * 136 + ks * 32 + qd * 8];
#pragma unroll
        for (int ti = 0; ti < 2; ++ti)
          acc1[ti][tjj] =
              __builtin_amdgcn_mfma_f32_16x16x32_bf16(afp[ti][ks], bf, acc1[ti][tjj], 0, 0, 0);
      }
    __builtin_amdgcn_s_setprio(0);
    if (q < 3) bar_lds();  // sB reads done before next stage; q=3: pre-p2 bar covers
    // ---- P-write: p = ww*4 + q (wave-uniform); swizzled kappa slots ----
#pragma unroll
    for (int ti = 0; ti < 2; ++ti) {
      int cbase = 16 * ti + qd * 4;
      int cb = cbase >> 3;
#pragma unroll
      for (int tjj = 0; tjj < 2; ++tjj) {
        int d = 16 * tjj + ln;
        int p = ww * 4 + q;
        uint2 u;
        u.x = pack_bf2(acc1[ti][tjj][0], acc1[ti][tjj][1]);
        u.y = pack_bf2(acc1[ti][tjj][2], acc1[ti][tjj][3]);
        *(uint2*)&sP[p * 1032 + d * 32 + ((((d >> 1) & 3) ^ cb) * 8) + (cbase & 7)] = u;
      }
    }
  }

  // ---- WF head-hoist: issue first 4 cc x 2 zt fragment loads BEFORE the barrier ----
  short8 wpre[4][2];
#pragma unroll
  for (int cc = 0; cc < 4; ++cc)
#pragma unroll
    for (int h2 = 0; h2 < 2; ++h2)
      wpre[cc][h2] = *(const short8*)(
          WF + ((size_t)((ztp * 2 + h2) * 32 + kq * 16 + cc) * 64 + lane) * 8);

  bar_lds();  // all P-writes visible; wpre stays in flight

  // ---- p2: operand-swapped mfma(W, P); WF streamed from L2 ----
  f32x4 acc2[2][2];  // [h2][mt]
#pragma unroll
  for (int a = 0; a < 2; ++a)
#pragma unroll
    for (int b = 0; b < 2; ++b) acc2[a][b] = (f32x4){0.f, 0.f, 0.f, 0.f};
  __builtin_amdgcn_s_setprio(1);
#pragma unroll
  for (int cc = 0; cc < 16; ++cc) {
    int ks = kq * 16 + cc;
    int swz = ((((ks >> 1) & 3) ^ qd) * 8);
    short8 afr[2];  // [mt]
#pragma unroll
    for (int mt = 0; mt < 2; ++mt)
      afr[mt] = *(const short8*)&sP[(mt * 16 + ln) * 1032 + ks * 32 + swz];
#pragma unroll
    for (int h2 = 0; h2 < 2; ++h2) {
      int zt = ztp * 2 + h2;
      short8 bfr = (cc < 4) ? wpre[cc][h2]
                            : *(const short8*)(WF + ((size_t)(zt * 32 + ks) * 64 + lane) * 8);
#pragma unroll
      for (int mt = 0; mt < 2; ++mt)  // SWAPPED: D[m=z][n=p]
        acc2[h2][mt] =
            __builtin_amdgcn_mfma_f32_16x16x32_bf16(bfr, afr[mt], acc2[h2][mt], 0, 0, 0);
    }
  }
  __builtin_amdgcn_s_setprio(0);
  bar_lds();  // all sP reads done -> redR overlay safe

  // ---- kq 2-way reduction via lane-linear redR slots (16 x 1KB) ----
  if (kq == 1) {
#pragma unroll
    for (int h2 = 0; h2 < 2; ++h2)
#pragma unroll
      for (int mt = 0; mt < 2; ++mt)
        *(f32x4*)&redR[(((ztp * 2 + h2) * 2 + mt) << 8) + lane * 4] = acc2[h2][mt];
  }
  bar_lds();
  if (kq == 0) {
#pragma unroll
    for (int h2 = 0; h2 < 2; ++h2) {
      int z = (ztp * 2 + h2) * 16 + qd * 4;
      f32x4 bz = *(const f32x4*)(bout + z);
#pragma unroll
      for (int mt = 0; mt < 2; ++mt) {
        int p = mt * 16 + ln;
        f32x4 v = acc2[h2][mt] +
                  *(const f32x4*)&redR[(((ztp * 2 + h2) * 2 + mt) << 8) + lane * 4] + bz;
        int i = i0 + (p >> 2), j = jg * 4 + (p & 3);
        *(f32x4*)&out[((size_t)i * IDIM + j) * CZ + z] = v;
      }
    }
  }
}

extern "C" void kernel_launch(void* const* d_in, const int* in_sizes, int n_in,
                              void* d_out, int out_size, void* d_ws, size_t ws_size,
                              hipStream_t stream) {
  const float* msa = (const float*)d_in[0];
  const float* lnw = (const float*)d_in[1];
  const float* lnb = (const float*)d_in[2];
  const float* wl  = (const float*)d_in[3];
  const float* bl  = (const float*)d_in[4];
  const float* wr  = (const float*)d_in[5];
  const float* br  = (const float*)d_in[6];
  const float* wo  = (const float*)d_in[7];
  const float* bo  = (const float*)d_in[8];
  float* out = (float*)d_out;

  char* ws = (char*)d_ws;
  unsigned short* A2    = (unsigned short*)ws;                         // 2 MB (frag-major)
  unsigned short* Bbuf  = (unsigned short*)(ws + (2u << 20));          // 2 MB (row-major)
  unsigned short* wlrT2 = (unsigned short*)(ws + (4u << 20));          // 32 KB (frag-major)
  unsigned short* WF    = (unsigned short*)(ws + (4u << 20) + 32768);  // 256 KB

  (void)hipFuncSetAttribute((const void*)k_main,
                            hipFuncAttributeMaxDynamicSharedMemorySize, 74752);

  k_prep<<<72, 256, 0, stream>>>(wl, wr, wo, wlrT2, WF);
  k_lnproj<<<dim3(256, 2), 512, 0, stream>>>(msa, lnw, lnb, bl, br, wlrT2, A2, Bbuf);
  k_main<<<2048, 512, 74752, stream>>>(A2, Bbuf, WF, bo, out);
}